// Round 3
// baseline (160.655 us; speedup 1.0000x reference)
//
#include <hip/hip_runtime.h>
#include <hip/hip_bf16.h>

// Skipgram negative-sampling loss on MI355X — round 12.
// R9=148.4 (8-lane fp8 gather). R10 FAILED (load-batch serialized).
// R11=148.6: occupancy trim = EXACT ZERO -> grid is only 8 waves/SIMD of
// total work, already fully resident; occupancy was never binding.
// Revised theory: gather is RANDOM-ACCESS HBM THROUGHPUT bound (R10 counters:
// FETCH 54MB in the gather = whole working set from HBM each iter, because
// the 268MB poison-fill wipes L3; 54MB/35us = 1.6 TB/s = random-gather
// ceiling). Fix: stage W_in as bf16 into ws too -> convert reads it
// STREAMING at 6.3TB/s and gather then hits L2/L3 (38.4MB staged << 256MB
// L3, written after the fill). Gather W_in bytes also halve (512->256B).

#define N_SAMPLES 65536
#define N_DIMS 128
#define K_NEG 10
#define N_WORDS 100000
#define WOUT_FP8_BYTES  ((size_t)N_WORDS * N_DIMS)      // 12.8 MB
#define WIN_BF16_OFF    WOUT_FP8_BYTES
#define WIN_BF16_BYTES  ((size_t)N_WORDS * N_DIMS * 2)  // 25.6 MB
#define WS_NEED         (WOUT_FP8_BYTES + WIN_BF16_BYTES)

__global__ void zero_out_kernel(float* out) {
    if (threadIdx.x == 0 && blockIdx.x == 0) out[0] = 0.0f;
}

__device__ __forceinline__ float log_sigmoid_fast(float x) {
    float ax = fabsf(x);
    return fminf(x, 0.0f) - __logf(1.0f + __expf(-ax));
}

__device__ __forceinline__ float dot4(float4 a, float4 b) {
    return a.x * b.x + a.y * b.y + a.z * b.z + a.w * b.w;
}

__device__ __forceinline__ float group8_reduce(float v) {
    v += __shfl_xor(v, 4);
    v += __shfl_xor(v, 2);
    v += __shfl_xor(v, 1);
    return v;
}

// RNE f32 -> bf16 pair packed into one uint (inputs are finite, no NaN care).
__device__ __forceinline__ unsigned pack_bf16(float x, float y) {
    unsigned ux = __float_as_uint(x), uy = __float_as_uint(y);
    ux = (ux + 0x7FFFu + ((ux >> 16) & 1u)) >> 16;
    uy = (uy + 0x7FFFu + ((uy >> 16) & 1u)) >> 16;
    return ux | (uy << 16);
}

__device__ __forceinline__ float2 bf16x2_to_f32(unsigned u) {
    return make_float2(__uint_as_float(u << 16),
                       __uint_as_float(u & 0xFFFF0000u));
}

// ---- Fused staging kernel: W_out->fp8 (12.8MB) + W_in->bf16 (25.6MB) ------
// Streaming: reads 102.4MB, writes 38.4MB, one launch. Also zeroes out[0].
__global__ __launch_bounds__(256) void convert_kernel(
        const float* __restrict__ W_out, const float* __restrict__ W_in,
        unsigned char* __restrict__ ws, float* __restrict__ out)
{
    if (blockIdx.x == 0 && threadIdx.x == 0) out[0] = 0.0f;
    const int NOUT16 = N_WORDS * N_DIMS / 16;   // 800000 (16 fp8 per thread)
    const int NIN8   = N_WORDS * N_DIMS / 8;    // 1600000 (8 bf16 per thread)
    const int tid = blockIdx.x * 256 + threadIdx.x;
    if (tid < NOUT16) {
        const float4* __restrict__ src = (const float4*)W_out;
        float4 f0 = src[4 * tid + 0];
        float4 f1 = src[4 * tid + 1];
        float4 f2 = src[4 * tid + 2];
        float4 f3 = src[4 * tid + 3];
        uint4 p;
        p.x = __builtin_amdgcn_cvt_pk_fp8_f32(f0.z, f0.w,
              __builtin_amdgcn_cvt_pk_fp8_f32(f0.x, f0.y, 0u, false), true);
        p.y = __builtin_amdgcn_cvt_pk_fp8_f32(f1.z, f1.w,
              __builtin_amdgcn_cvt_pk_fp8_f32(f1.x, f1.y, 0u, false), true);
        p.z = __builtin_amdgcn_cvt_pk_fp8_f32(f2.z, f2.w,
              __builtin_amdgcn_cvt_pk_fp8_f32(f2.x, f2.y, 0u, false), true);
        p.w = __builtin_amdgcn_cvt_pk_fp8_f32(f3.z, f3.w,
              __builtin_amdgcn_cvt_pk_fp8_f32(f3.x, f3.y, 0u, false), true);
        ((uint4*)ws)[tid] = p;
    } else {
        const int j = tid - NOUT16;
        if (j < NIN8) {
            const float4* __restrict__ src = (const float4*)W_in;
            float4 f0 = src[2 * j + 0];
            float4 f1 = src[2 * j + 1];
            uint4 p;
            p.x = pack_bf16(f0.x, f0.y);
            p.y = pack_bf16(f0.z, f0.w);
            p.z = pack_bf16(f1.x, f1.y);
            p.w = pack_bf16(f1.z, f1.w);
            ((uint4*)(ws + WIN_BF16_OFF))[j] = p;
        }
    }
}

// ---- fp8 word (4 dims) vs two bf16-derived float2 pairs -------------------
__device__ __forceinline__ float dot_word_fp8(float2 a01, float2 a23,
                                              unsigned w, float acc) {
    auto p0 = __builtin_amdgcn_cvt_pk_f32_fp8(w, false);  // elements 0,1
    auto p1 = __builtin_amdgcn_cvt_pk_f32_fp8(w, true);   // elements 2,3
    acc = fmaf(a01.x, p0[0], acc);
    acc = fmaf(a01.y, p0[1], acc);
    acc = fmaf(a23.x, p1[0], acc);
    acc = fmaf(a23.y, p1[1], acc);
    return acc;
}

// ---- Gather kernel: 8 lanes/sample, both tables staged in ws (L2/L3-hot) --
// Lane g holds dims [16g..16g+15]: bf16 a-row = 2 x uint4 (32B), each fp8
// row = 1 x uint4 (16B). 13 VMEM in one batch; 32-bit SADDR offsets.
__global__ __launch_bounds__(256, 6) void skipgram_fp8_kernel(
        const int* __restrict__ input_idx,
        const int* __restrict__ output_idx,
        const int* __restrict__ neg_idx,
        const unsigned char* __restrict__ ws,
        float* __restrict__ out)
{
    const int g = threadIdx.x & 7;                               // lane in group
    const int n = (blockIdx.x * blockDim.x + threadIdx.x) >> 3;  // sample id

    // All 12 indices up front. neg_idx base n*10 ints = 40n bytes: always
    // 8-aligned -> 5x int2 loads. (HW-broadcast within the 8-lane group.)
    int idx[12];
    idx[0] = input_idx[n];
    idx[1] = output_idx[n];
    const int2* __restrict__ np = (const int2*)(neg_idx + (size_t)n * K_NEG);
    #pragma unroll
    for (int k = 0; k < 5; ++k) {
        int2 v = np[k];
        idx[2 + 2 * k]     = v.x;
        idx[2 + 2 * k + 1] = v.y;
    }

    // Input row bf16 from ws: lane g reads 32B at idx0*256 + 32g.
    const unsigned char* __restrict__ Wi16 = ws + WIN_BF16_OFF;
    const unsigned aoff = (unsigned)idx[0] * (unsigned)(N_DIMS * 2) + 32u * g;
    uint4 u0 = *(const uint4*)(Wi16 + aoff);
    uint4 u1 = *(const uint4*)(Wi16 + aoff + 16u);

    // 11 gathered fp8 rows: lane g reads bytes [16g..16g+15] = 1 x uint4.
    uint4 r[11];
    #pragma unroll
    for (int t = 0; t < 11; ++t) {
        const unsigned off = (unsigned)idx[1 + t] * (unsigned)N_DIMS + 16u * g;
        r[t] = *(const uint4*)(ws + off);
    }

    // Pin: loads may not sink below this point.
    __builtin_amdgcn_sched_barrier(0);

    // Unpack a-row once (u0/u1 die, 16 f32 live).
    float2 A[8];
    A[0] = bf16x2_to_f32(u0.x); A[1] = bf16x2_to_f32(u0.y);
    A[2] = bf16x2_to_f32(u0.z); A[3] = bf16x2_to_f32(u0.w);
    A[4] = bf16x2_to_f32(u1.x); A[5] = bf16x2_to_f32(u1.y);
    A[6] = bf16x2_to_f32(u1.z); A[7] = bf16x2_to_f32(u1.w);

    float acc = 0.0f;
    #pragma unroll
    for (int t = 0; t < 11; ++t) {
        float d = 0.0f;
        d = dot_word_fp8(A[0], A[1], r[t].x, d);
        d = dot_word_fp8(A[2], A[3], r[t].y, d);
        d = dot_word_fp8(A[4], A[5], r[t].z, d);
        d = dot_word_fp8(A[6], A[7], r[t].w, d);
        d = group8_reduce(d);
        acc += log_sigmoid_fast(t == 0 ? d : -d);
    }

    __shared__ float sdata[32];
    if (g == 0) sdata[threadIdx.x >> 3] = acc;
    __syncthreads();
    if (threadIdx.x < 32) {
        float s = sdata[threadIdx.x];
        s += __shfl_xor(s, 16);
        s += __shfl_xor(s, 8);
        s += __shfl_xor(s, 4);
        s += __shfl_xor(s, 2);
        s += __shfl_xor(s, 1);
        if (threadIdx.x == 0)
            atomicAdd(out, s * (1.0f / (float)N_SAMPLES));
    }
}

// ---- Fallback fp32 path (R5 kernel) in case ws_size < 38.4 MB -------------
__global__ __launch_bounds__(256, 2) void skipgram_f32_kernel(
        const int* __restrict__ input_idx,
        const int* __restrict__ output_idx,
        const int* __restrict__ neg_idx,
        const float* __restrict__ W_in,
        const float* __restrict__ W_out,
        float* __restrict__ out)
{
    const int g = threadIdx.x & 7;
    const int n = (blockIdx.x * blockDim.x + threadIdx.x) >> 3;

    int idx[12];
    idx[0] = input_idx[n];
    idx[1] = output_idx[n];
    #pragma unroll
    for (int k = 0; k < K_NEG; ++k) idx[2 + k] = neg_idx[n * K_NEG + k];

    const float4* __restrict__ arow = (const float4*)(W_in + (size_t)idx[0] * N_DIMS);
    float4 a0 = arow[0 * 8 + g];
    float4 a1 = arow[1 * 8 + g];
    float4 a2 = arow[2 * 8 + g];
    float4 a3 = arow[3 * 8 + g];

    float4 r[11][4];
    #pragma unroll
    for (int t = 0; t < 11; ++t) {
        const float4* __restrict__ rr =
            (const float4*)(W_out + (size_t)idx[1 + t] * N_DIMS);
        r[t][0] = rr[0 * 8 + g];
        r[t][1] = rr[1 * 8 + g];
        r[t][2] = rr[2 * 8 + g];
        r[t][3] = rr[3 * 8 + g];
    }
    __builtin_amdgcn_sched_barrier(0);

    float acc = 0.0f;
    #pragma unroll
    for (int t = 0; t < 11; ++t) {
        float d = dot4(a0, r[t][0]) + dot4(a1, r[t][1])
                + dot4(a2, r[t][2]) + dot4(a3, r[t][3]);
        d = group8_reduce(d);
        acc += log_sigmoid_fast(t == 0 ? d : -d);
    }

    __shared__ float sdata[32];
    if (g == 0) sdata[threadIdx.x >> 3] = acc;
    __syncthreads();
    if (threadIdx.x < 32) {
        float s = sdata[threadIdx.x];
        s += __shfl_xor(s, 16);
        s += __shfl_xor(s, 8);
        s += __shfl_xor(s, 4);
        s += __shfl_xor(s, 2);
        s += __shfl_xor(s, 1);
        if (threadIdx.x == 0)
            atomicAdd(out, s * (1.0f / (float)N_SAMPLES));
    }
}

extern "C" void kernel_launch(void* const* d_in, const int* in_sizes, int n_in,
                              void* d_out, int out_size, void* d_ws, size_t ws_size,
                              hipStream_t stream) {
    const int*   input_idx  = (const int*)d_in[0];
    const int*   output_idx = (const int*)d_in[1];
    const int*   neg_idx    = (const int*)d_in[2];
    const float* W_in       = (const float*)d_in[3];
    const float* W_out      = (const float*)d_in[4];
    float* out = (float*)d_out;

    const int block = 256;                       // 32 groups of 8 lanes
    const int grid  = N_SAMPLES / (block / 8);   // 2048 blocks, exact cover

    if (ws_size >= WS_NEED) {
        unsigned char* ws = (unsigned char*)d_ws;
        const int ctotal = N_WORDS * N_DIMS / 16 + N_WORDS * N_DIMS / 8;  // 2.4M
        const int cgrid  = (ctotal + 255) / 256;                          // 9375
        convert_kernel<<<cgrid, 256, 0, stream>>>(W_out, W_in, ws, out);
        skipgram_fp8_kernel<<<grid, block, 0, stream>>>(
            input_idx, output_idx, neg_idx, ws, out);
    } else {
        zero_out_kernel<<<1, 64, 0, stream>>>(out);
        skipgram_f32_kernel<<<grid, block, 0, stream>>>(
            input_idx, output_idx, neg_idx, W_in, W_out, out);
    }
}

// Round 5
// 160.587 us; speedup vs baseline: 1.0004x; 1.0004x over previous
//
#include <hip/hip_runtime.h>
#include <hip/hip_bf16.h>

// Skipgram negative-sampling loss on MI355X — round 14 (= R13 + compile fix).
// History: R9=148.4 (W_in fp32 direct + fp8 W_out gather, (256,4), ~90 VGPR,
//   gather 35us @ 1.55 TB/s random). R10/R12 FAILED the same way: any
//   launch_bounds tighter than (256,4) flips the scheduler into
//   register-minimizing mode (VGPR 24/36) which SERIALIZES the 13-load batch.
// R12 counters (despite serialization) proved staging cuts random bytes:
//   FETCH 54.3 -> 44.8 MB. Byte model: random BW ~1.55 TB/s is only 4x slower
//   than streaming, so staging pays iff (reuse x shrink) beats the extra
//   streaming. W_out (7.2 uses/row): big win. W_in bf16 (0.48 uses/row): loss
//   (R12). W_in fp8: marginal win (+64MB streaming vs -18MB random) AND
//   shrinks L2 footprint to 25.6MB total -> less cross-XCD refetch.
// R13 didn't compile: cvt_pk_f32_fp8 returns a NATIVE clang vector (v2f),
//   not HIP float2 — no implicit conversion. R14 uses ext_vector_type(2).

#define N_SAMPLES 65536
#define N_DIMS 128
#define K_NEG 10
#define N_WORDS 100000
#define WOUT_FP8_BYTES ((size_t)N_WORDS * N_DIMS)       // 12.8 MB
#define WIN_FP8_OFF    WOUT_FP8_BYTES
#define WIN_FP8_BYTES  ((size_t)N_WORDS * N_DIMS)       // 12.8 MB
#define WS_NEED        (WOUT_FP8_BYTES + WIN_FP8_BYTES) // 25.6 MB

typedef float v2f __attribute__((ext_vector_type(2)));

__global__ void zero_out_kernel(float* out) {
    if (threadIdx.x == 0 && blockIdx.x == 0) out[0] = 0.0f;
}

__device__ __forceinline__ float log_sigmoid_fast(float x) {
    float ax = fabsf(x);
    return fminf(x, 0.0f) - __logf(1.0f + __expf(-ax));
}

__device__ __forceinline__ float dot4(float4 a, float4 b) {
    return a.x * b.x + a.y * b.y + a.z * b.z + a.w * b.w;
}

__device__ __forceinline__ float group8_reduce(float v) {
    v += __shfl_xor(v, 4);
    v += __shfl_xor(v, 2);
    v += __shfl_xor(v, 1);
    return v;
}

// 16 fp32 (4x float4) -> 16 fp8 e4m3 packed in a uint4.
__device__ __forceinline__ uint4 pack16_fp8(float4 f0, float4 f1,
                                            float4 f2, float4 f3) {
    uint4 p;
    p.x = __builtin_amdgcn_cvt_pk_fp8_f32(f0.z, f0.w,
          __builtin_amdgcn_cvt_pk_fp8_f32(f0.x, f0.y, 0u, false), true);
    p.y = __builtin_amdgcn_cvt_pk_fp8_f32(f1.z, f1.w,
          __builtin_amdgcn_cvt_pk_fp8_f32(f1.x, f1.y, 0u, false), true);
    p.z = __builtin_amdgcn_cvt_pk_fp8_f32(f2.z, f2.w,
          __builtin_amdgcn_cvt_pk_fp8_f32(f2.x, f2.y, 0u, false), true);
    p.w = __builtin_amdgcn_cvt_pk_fp8_f32(f3.z, f3.w,
          __builtin_amdgcn_cvt_pk_fp8_f32(f3.x, f3.y, 0u, false), true);
    return p;
}

// ---- Fused staging: W_out->fp8 and W_in->fp8, both streaming --------------
// Reads 102.4 MB, writes 25.6 MB, one launch. Also zeroes out[0].
__global__ __launch_bounds__(256) void convert_kernel(
        const float* __restrict__ W_out, const float* __restrict__ W_in,
        unsigned char* __restrict__ ws, float* __restrict__ out)
{
    if (blockIdx.x == 0 && threadIdx.x == 0) out[0] = 0.0f;
    const int N16 = N_WORDS * N_DIMS / 16;   // 800000 per table
    const int tid = blockIdx.x * 256 + threadIdx.x;
    if (tid < N16) {
        const float4* __restrict__ src = (const float4*)W_out;
        ((uint4*)ws)[tid] = pack16_fp8(src[4 * tid + 0], src[4 * tid + 1],
                                       src[4 * tid + 2], src[4 * tid + 3]);
    } else {
        const int j = tid - N16;
        if (j < N16) {
            const float4* __restrict__ src = (const float4*)W_in;
            ((uint4*)(ws + WIN_FP8_OFF))[j] =
                pack16_fp8(src[4 * j + 0], src[4 * j + 1],
                           src[4 * j + 2], src[4 * j + 3]);
        }
    }
}

// ---- fp8 word (4 dims) vs two native-v2f pairs ----------------------------
__device__ __forceinline__ float dot_word_fp8(v2f a01, v2f a23,
                                              unsigned w, float acc) {
    v2f p0 = __builtin_amdgcn_cvt_pk_f32_fp8(w, false);  // elements 0,1
    v2f p1 = __builtin_amdgcn_cvt_pk_f32_fp8(w, true);   // elements 2,3
    acc = fmaf(a01[0], p0[0], acc);
    acc = fmaf(a01[1], p0[1], acc);
    acc = fmaf(a23[0], p1[0], acc);
    acc = fmaf(a23[1], p1[1], acc);
    return acc;
}

// ---- Gather: 8 lanes/sample, both tables fp8 in ws, full 13-load batch ----
// Lane g holds dims [16g..16g+15]: 1 uint4 of W_in-fp8 + 11 uint4 fp8 rows.
// launch_bounds(256,4): cap 128 VGPR — proven (R9) to keep ~90 live and the
// whole batch in flight. Tighter caps serialize the batch (R10/R12 lesson).
__global__ __launch_bounds__(256, 4) void skipgram_fp8_kernel(
        const int* __restrict__ input_idx,
        const int* __restrict__ output_idx,
        const int* __restrict__ neg_idx,
        const unsigned char* __restrict__ ws,
        float* __restrict__ out)
{
    const int g = threadIdx.x & 7;                               // lane in group
    const int n = (blockIdx.x * blockDim.x + threadIdx.x) >> 3;  // sample id

    // All 12 indices up front. neg_idx base n*10 ints = 40n bytes: always
    // 8-aligned -> 5x int2 loads. (HW-broadcast within the 8-lane group.)
    int idx[12];
    idx[0] = input_idx[n];
    idx[1] = output_idx[n];
    const int2* __restrict__ np = (const int2*)(neg_idx + (size_t)n * K_NEG);
    #pragma unroll
    for (int k = 0; k < 5; ++k) {
        int2 v = np[k];
        idx[2 + 2 * k]     = v.x;
        idx[2 + 2 * k + 1] = v.y;
    }

    // Input row fp8: lane g reads bytes [16g..16g+15] = 1 x uint4.
    const unsigned aoff = (unsigned)idx[0] * (unsigned)N_DIMS + 16u * g;
    uint4 au = *(const uint4*)(ws + WIN_FP8_OFF + aoff);

    // 11 gathered fp8 rows, 32-bit SADDR offsets.
    uint4 r[11];
    #pragma unroll
    for (int t = 0; t < 11; ++t) {
        const unsigned off = (unsigned)idx[1 + t] * (unsigned)N_DIMS + 16u * g;
        r[t] = *(const uint4*)(ws + off);
    }

    // Pin: loads may not sink below this point.
    __builtin_amdgcn_sched_barrier(0);

    // Unpack a-row once (au dies, 16 f32 live).
    v2f A[8];
    A[0] = __builtin_amdgcn_cvt_pk_f32_fp8(au.x, false);
    A[1] = __builtin_amdgcn_cvt_pk_f32_fp8(au.x, true);
    A[2] = __builtin_amdgcn_cvt_pk_f32_fp8(au.y, false);
    A[3] = __builtin_amdgcn_cvt_pk_f32_fp8(au.y, true);
    A[4] = __builtin_amdgcn_cvt_pk_f32_fp8(au.z, false);
    A[5] = __builtin_amdgcn_cvt_pk_f32_fp8(au.z, true);
    A[6] = __builtin_amdgcn_cvt_pk_f32_fp8(au.w, false);
    A[7] = __builtin_amdgcn_cvt_pk_f32_fp8(au.w, true);

    float acc = 0.0f;
    #pragma unroll
    for (int t = 0; t < 11; ++t) {
        float d = 0.0f;
        d = dot_word_fp8(A[0], A[1], r[t].x, d);
        d = dot_word_fp8(A[2], A[3], r[t].y, d);
        d = dot_word_fp8(A[4], A[5], r[t].z, d);
        d = dot_word_fp8(A[6], A[7], r[t].w, d);
        d = group8_reduce(d);
        acc += log_sigmoid_fast(t == 0 ? d : -d);
    }

    __shared__ float sdata[32];
    if (g == 0) sdata[threadIdx.x >> 3] = acc;
    __syncthreads();
    if (threadIdx.x < 32) {
        float s = sdata[threadIdx.x];
        s += __shfl_xor(s, 16);
        s += __shfl_xor(s, 8);
        s += __shfl_xor(s, 4);
        s += __shfl_xor(s, 2);
        s += __shfl_xor(s, 1);
        if (threadIdx.x == 0)
            atomicAdd(out, s * (1.0f / (float)N_SAMPLES));
    }
}

// ---- Fallback fp32 path (R5 kernel) in case ws_size < 25.6 MB -------------
__global__ __launch_bounds__(256, 2) void skipgram_f32_kernel(
        const int* __restrict__ input_idx,
        const int* __restrict__ output_idx,
        const int* __restrict__ neg_idx,
        const float* __restrict__ W_in,
        const float* __restrict__ W_out,
        float* __restrict__ out)
{
    const int g = threadIdx.x & 7;
    const int n = (blockIdx.x * blockDim.x + threadIdx.x) >> 3;

    int idx[12];
    idx[0] = input_idx[n];
    idx[1] = output_idx[n];
    #pragma unroll
    for (int k = 0; k < K_NEG; ++k) idx[2 + k] = neg_idx[n * K_NEG + k];

    const float4* __restrict__ arow = (const float4*)(W_in + (size_t)idx[0] * N_DIMS);
    float4 a0 = arow[0 * 8 + g];
    float4 a1 = arow[1 * 8 + g];
    float4 a2 = arow[2 * 8 + g];
    float4 a3 = arow[3 * 8 + g];

    float4 r[11][4];
    #pragma unroll
    for (int t = 0; t < 11; ++t) {
        const float4* __restrict__ rr =
            (const float4*)(W_out + (size_t)idx[1 + t] * N_DIMS);
        r[t][0] = rr[0 * 8 + g];
        r[t][1] = rr[1 * 8 + g];
        r[t][2] = rr[2 * 8 + g];
        r[t][3] = rr[3 * 8 + g];
    }
    __builtin_amdgcn_sched_barrier(0);

    float acc = 0.0f;
    #pragma unroll
    for (int t = 0; t < 11; ++t) {
        float d = dot4(a0, r[t][0]) + dot4(a1, r[t][1])
                + dot4(a2, r[t][2]) + dot4(a3, r[t][3]);
        d = group8_reduce(d);
        acc += log_sigmoid_fast(t == 0 ? d : -d);
    }

    __shared__ float sdata[32];
    if (g == 0) sdata[threadIdx.x >> 3] = acc;
    __syncthreads();
    if (threadIdx.x < 32) {
        float s = sdata[threadIdx.x];
        s += __shfl_xor(s, 16);
        s += __shfl_xor(s, 8);
        s += __shfl_xor(s, 4);
        s += __shfl_xor(s, 2);
        s += __shfl_xor(s, 1);
        if (threadIdx.x == 0)
            atomicAdd(out, s * (1.0f / (float)N_SAMPLES));
    }
}

extern "C" void kernel_launch(void* const* d_in, const int* in_sizes, int n_in,
                              void* d_out, int out_size, void* d_ws, size_t ws_size,
                              hipStream_t stream) {
    const int*   input_idx  = (const int*)d_in[0];
    const int*   output_idx = (const int*)d_in[1];
    const int*   neg_idx    = (const int*)d_in[2];
    const float* W_in       = (const float*)d_in[3];
    const float* W_out      = (const float*)d_in[4];
    float* out = (float*)d_out;

    const int block = 256;                       // 32 groups of 8 lanes
    const int grid  = N_SAMPLES / (block / 8);   // 2048 blocks, exact cover

    if (ws_size >= WS_NEED) {
        unsigned char* ws = (unsigned char*)d_ws;
        const int ctotal = 2 * (N_WORDS * N_DIMS / 16);   // 1.6M threads
        const int cgrid  = (ctotal + 255) / 256;          // 6250
        convert_kernel<<<cgrid, 256, 0, stream>>>(W_out, W_in, ws, out);
        skipgram_fp8_kernel<<<grid, block, 0, stream>>>(
            input_idx, output_idx, neg_idx, ws, out);
    } else {
        zero_out_kernel<<<1, 64, 0, stream>>>(out);
        skipgram_f32_kernel<<<grid, block, 0, stream>>>(
            input_idx, output_idx, neg_idx, W_in, W_out, out);
    }
}

// Round 6
// 148.622 us; speedup vs baseline: 1.0810x; 1.0805x over previous
//
#include <hip/hip_runtime.h>
#include <hip/hip_bf16.h>

// Skipgram negative-sampling loss on MI355X — round 15.
// Best known: R9 = 148.4us (W_in fp32 direct + fp8 W_out staged, 8-lane
// groups, (256,4) -> ~90 VGPR, full 15-load batch in flight).
// Failed branches, with causes:
//   R10/R12: launch_bounds tighter than (256,4) -> register-minimizing
//     scheduler serializes the load batch (VGPR 24/36). -14/-26us.
//   R11: +50% occupancy headroom -> EXACT ZERO (grid is only 8 waves/SIMD
//     total, already fully resident; occupancy never binding).
//   R14: W_in staged fp8 -> Dtotal = +convert streaming only; gather
//     UNCHANGED despite W_in random bytes 33MB->6MB. Conclusion: gather is
//     bound by the W_out random request stream (720k x 128B through L2-miss
//     path), W_in cost hides under it. Do NOT stage W_in.
// R15 = R9 + nontemporal hints on W_in/index loads: used-once streams no
// longer thrash per-XCD L2 -> more of the 12.8MB fp8 W_out table stays
// resident -> higher hit rate on the DOMINANT request stream.

#define N_SAMPLES 65536
#define N_DIMS 128
#define K_NEG 10
#define N_WORDS 100000
#define WOUT_FP8_BYTES ((size_t)N_WORDS * N_DIMS)   // 12.8 MB

typedef float v4f __attribute__((ext_vector_type(4)));
typedef float v2f __attribute__((ext_vector_type(2)));
typedef int   v2i __attribute__((ext_vector_type(2)));

__global__ void zero_out_kernel(float* out) {
    if (threadIdx.x == 0 && blockIdx.x == 0) out[0] = 0.0f;
}

__device__ __forceinline__ float log_sigmoid_fast(float x) {
    float ax = fabsf(x);
    return fminf(x, 0.0f) - __logf(1.0f + __expf(-ax));
}

__device__ __forceinline__ float dot4(float4 a, float4 b) {
    return a.x * b.x + a.y * b.y + a.z * b.z + a.w * b.w;
}

__device__ __forceinline__ float group8_reduce(float v) {
    v += __shfl_xor(v, 4);
    v += __shfl_xor(v, 2);
    v += __shfl_xor(v, 1);
    return v;
}

// ---- fp32 -> fp8 e4m3 (OCP) streaming conversion into d_ws ----------------
// One uint4 (16 fp8) per thread-iteration: 4x float4 in, 1x uint4 out.
__global__ __launch_bounds__(256) void convert_fp8_kernel(
        const float* __restrict__ W_out, uint4* __restrict__ dst,
        float* __restrict__ out)
{
    if (blockIdx.x == 0 && threadIdx.x == 0) out[0] = 0.0f;  // fold zero_out in
    const size_t total16 = (size_t)N_WORDS * N_DIMS / 16;    // 800000
    const size_t i = blockIdx.x * (size_t)blockDim.x + threadIdx.x;
    if (i >= total16) return;
    const float4* __restrict__ src = (const float4*)W_out;
    float4 f0 = src[4 * i + 0];
    float4 f1 = src[4 * i + 1];
    float4 f2 = src[4 * i + 2];
    float4 f3 = src[4 * i + 3];
    uint4 p;
    p.x = __builtin_amdgcn_cvt_pk_fp8_f32(f0.z, f0.w,
          __builtin_amdgcn_cvt_pk_fp8_f32(f0.x, f0.y, 0u, false), true);
    p.y = __builtin_amdgcn_cvt_pk_fp8_f32(f1.z, f1.w,
          __builtin_amdgcn_cvt_pk_fp8_f32(f1.x, f1.y, 0u, false), true);
    p.z = __builtin_amdgcn_cvt_pk_fp8_f32(f2.z, f2.w,
          __builtin_amdgcn_cvt_pk_fp8_f32(f2.x, f2.y, 0u, false), true);
    p.w = __builtin_amdgcn_cvt_pk_fp8_f32(f3.z, f3.w,
          __builtin_amdgcn_cvt_pk_fp8_f32(f3.x, f3.y, 0u, false), true);
    dst[i] = p;
}

// ---- fp8 row dot: lane holds 16 fp8 (uint4) + 16 fp32 dims (4x v4f) -------
__device__ __forceinline__ float dot_word_fp8(v4f a, unsigned int w, float acc) {
    v2f p0 = __builtin_amdgcn_cvt_pk_f32_fp8(w, false);  // elements 0,1
    v2f p1 = __builtin_amdgcn_cvt_pk_f32_fp8(w, true);   // elements 2,3
    acc = fmaf(a[0], p0[0], acc);
    acc = fmaf(a[1], p0[1], acc);
    acc = fmaf(a[2], p1[0], acc);
    acc = fmaf(a[3], p1[1], acc);
    return acc;
}

__device__ __forceinline__ float dot_row_fp8(const v4f a0, const v4f a1,
                                             const v4f a2, const v4f a3,
                                             const uint4 b) {
    float acc = 0.0f;
    acc = dot_word_fp8(a0, b.x, acc);
    acc = dot_word_fp8(a1, b.y, acc);
    acc = dot_word_fp8(a2, b.z, acc);
    acc = dot_word_fp8(a3, b.w, acc);
    return acc;
}

// ---- Gather kernel: fp8 W_out rows (128 B), contiguous-16-dims per lane ----
// Identical load structure to R9 (proven full-MLP regime); the only change
// is cache policy: nt on used-once W_in/index streams, cached on W_out rows.
__global__ __launch_bounds__(256, 4) void skipgram_fp8_kernel(
        const int* __restrict__ input_idx,
        const int* __restrict__ output_idx,
        const int* __restrict__ neg_idx,
        const float* __restrict__ W_in,
        const unsigned char* __restrict__ Wo8,
        float* __restrict__ out)
{
    const int g = threadIdx.x & 7;                               // lane in group
    const int n = (blockIdx.x * blockDim.x + threadIdx.x) >> 3;  // sample id

    // All 12 indices up front. neg_idx base n*10 ints = 40n bytes: always
    // 8-aligned -> 5x int2 loads. nt: index arrays are used-once streams.
    int idx[12];
    idx[0] = __builtin_nontemporal_load(&input_idx[n]);
    idx[1] = __builtin_nontemporal_load(&output_idx[n]);
    const v2i* __restrict__ np = (const v2i*)(neg_idx + (size_t)n * K_NEG);
    #pragma unroll
    for (int k = 0; k < 5; ++k) {
        v2i v = __builtin_nontemporal_load(&np[k]);
        idx[2 + 2 * k]     = v[0];
        idx[2 + 2 * k + 1] = v[1];
    }

    // Input row fp32: lane g holds dims [16g..16g+15] = float4 slots 4g..4g+3.
    // nt: W_in rows are effectively used-once (0.65 draws/row) — don't let
    // them evict the fp8 W_out table from per-XCD L2.
    const v4f* __restrict__ arow = (const v4f*)(W_in + (size_t)idx[0] * N_DIMS);
    v4f a0 = __builtin_nontemporal_load(&arow[4 * g + 0]);
    v4f a1 = __builtin_nontemporal_load(&arow[4 * g + 1]);
    v4f a2 = __builtin_nontemporal_load(&arow[4 * g + 2]);
    v4f a3 = __builtin_nontemporal_load(&arow[4 * g + 3]);

    // 11 gathered fp8 rows: lane g reads bytes [16g..16g+15] = 1 x uint4.
    // Cached (default): 7.2 uses/row — this is the stream L2 should hold.
    uint4 r[11];
    #pragma unroll
    for (int t = 0; t < 11; ++t)
        r[t] = *(const uint4*)(Wo8 + (size_t)idx[1 + t] * N_DIMS + 16 * g);

    // Pin: loads may not sink below this point.
    __builtin_amdgcn_sched_barrier(0);

    float acc = 0.0f;
    #pragma unroll
    for (int t = 0; t < 11; ++t) {
        float d = dot_row_fp8(a0, a1, a2, a3, r[t]);
        d = group8_reduce(d);
        acc += log_sigmoid_fast(t == 0 ? d : -d);
    }

    __shared__ float sdata[32];
    if (g == 0) sdata[threadIdx.x >> 3] = acc;
    __syncthreads();
    if (threadIdx.x < 32) {
        float s = sdata[threadIdx.x];
        s += __shfl_xor(s, 16);
        s += __shfl_xor(s, 8);
        s += __shfl_xor(s, 4);
        s += __shfl_xor(s, 2);
        s += __shfl_xor(s, 1);
        if (threadIdx.x == 0)
            atomicAdd(out, s * (1.0f / (float)N_SAMPLES));
    }
}

// ---- Fallback fp32 path (R5 kernel) in case ws_size < 12.8 MB -------------
__global__ __launch_bounds__(256, 2) void skipgram_f32_kernel(
        const int* __restrict__ input_idx,
        const int* __restrict__ output_idx,
        const int* __restrict__ neg_idx,
        const float* __restrict__ W_in,
        const float* __restrict__ W_out,
        float* __restrict__ out)
{
    const int g = threadIdx.x & 7;
    const int n = (blockIdx.x * blockDim.x + threadIdx.x) >> 3;

    int idx[12];
    idx[0] = input_idx[n];
    idx[1] = output_idx[n];
    #pragma unroll
    for (int k = 0; k < K_NEG; ++k) idx[2 + k] = neg_idx[n * K_NEG + k];

    const float4* __restrict__ arow = (const float4*)(W_in + (size_t)idx[0] * N_DIMS);
    float4 a0 = arow[0 * 8 + g];
    float4 a1 = arow[1 * 8 + g];
    float4 a2 = arow[2 * 8 + g];
    float4 a3 = arow[3 * 8 + g];

    float4 r[11][4];
    #pragma unroll
    for (int t = 0; t < 11; ++t) {
        const float4* __restrict__ rr =
            (const float4*)(W_out + (size_t)idx[1 + t] * N_DIMS);
        r[t][0] = rr[0 * 8 + g];
        r[t][1] = rr[1 * 8 + g];
        r[t][2] = rr[2 * 8 + g];
        r[t][3] = rr[3 * 8 + g];
    }
    __builtin_amdgcn_sched_barrier(0);

    float acc = 0.0f;
    #pragma unroll
    for (int t = 0; t < 11; ++t) {
        float d = dot4(a0, r[t][0]) + dot4(a1, r[t][1])
                + dot4(a2, r[t][2]) + dot4(a3, r[t][3]);
        d = group8_reduce(d);
        acc += log_sigmoid_fast(t == 0 ? d : -d);
    }

    __shared__ float sdata[32];
    if (g == 0) sdata[threadIdx.x >> 3] = acc;
    __syncthreads();
    if (threadIdx.x < 32) {
        float s = sdata[threadIdx.x];
        s += __shfl_xor(s, 16);
        s += __shfl_xor(s, 8);
        s += __shfl_xor(s, 4);
        s += __shfl_xor(s, 2);
        s += __shfl_xor(s, 1);
        if (threadIdx.x == 0)
            atomicAdd(out, s * (1.0f / (float)N_SAMPLES));
    }
}

extern "C" void kernel_launch(void* const* d_in, const int* in_sizes, int n_in,
                              void* d_out, int out_size, void* d_ws, size_t ws_size,
                              hipStream_t stream) {
    const int*   input_idx  = (const int*)d_in[0];
    const int*   output_idx = (const int*)d_in[1];
    const int*   neg_idx    = (const int*)d_in[2];
    const float* W_in       = (const float*)d_in[3];
    const float* W_out      = (const float*)d_in[4];
    float* out = (float*)d_out;

    const int block = 256;                       // 32 groups of 8 lanes
    const int grid  = N_SAMPLES / (block / 8);   // 2048 blocks, exact cover

    if (ws_size >= WOUT_FP8_BYTES) {
        uint4* Wo8 = (uint4*)d_ws;
        const int ctotal = (int)((size_t)N_WORDS * N_DIMS / 16);  // 800000
        const int cgrid  = (ctotal + 255) / 256;                  // 3125
        convert_fp8_kernel<<<cgrid, 256, 0, stream>>>(W_out, Wo8, out);
        skipgram_fp8_kernel<<<grid, block, 0, stream>>>(
            input_idx, output_idx, neg_idx, W_in,
            (const unsigned char*)Wo8, out);
    } else {
        zero_out_kernel<<<1, 64, 0, stream>>>(out);
        skipgram_f32_kernel<<<grid, block, 0, stream>>>(
            input_idx, output_idx, neg_idx, W_in, W_out, out);
    }
}